// Round 1
// baseline (388.658 us; speedup 1.0000x reference)
//
#include <hip/hip_runtime.h>
#include <hip/hip_bf16.h>
#include <stdint.h>

// Problem constants
#define B_    256
#define LS_   1024
#define LW_   1024
#define LV_   1024
#define M_    16
#define D_    5120
#define H_    2048
#define ROWS  4096   // B*M
#define N1    4096   // H (eta) + H (rho) fused

typedef __hip_bfloat16 bf16;
typedef __bf16 bf16x8 __attribute__((ext_vector_type(8)));
typedef float f32x4 __attribute__((ext_vector_type(4)));

// ---------------------------------------------------------------------------
// async global->LDS, 16B per lane. LDS dest must be linear wave-uniform base +
// lane*16 (we pass the per-lane pointer; HW uses the uniform base).
__device__ __forceinline__ void gld_lds16(const void* g, void* l) {
  auto gp = (const __attribute__((address_space(1))) uint32_t*)(uintptr_t)g;
  auto lp = (__attribute__((address_space(3))) uint32_t*)(uint32_t)(uintptr_t)l;
  __builtin_amdgcn_global_load_lds(gp, lp, 16, 0, 0);
}

// ---------------------------------------------------------------------------
// s_feat: [B, 2048] bf16 : [mag*cos(phi) | mag*sin(phi)]
__global__ void sfeat_kernel(const float* __restrict__ phi, bf16* __restrict__ sfeat) {
  int i = blockIdx.x * blockDim.x + threadIdx.x;   // 0..B*LS-1
  int b = i >> 10, l = i & 1023;
  float p = phi[i];
  float s, c;
  sincosf(p, &s, &c);
  sfeat[b * 2048 + l]        = __float2bfloat16(0.03125f * c);
  sfeat[b * 2048 + 1024 + l] = __float2bfloat16(0.03125f * s);
}

// ---------------------------------------------------------------------------
// Transpose f32 [R,C] -> bf16 [C,R]
__global__ void transpose_bf16_kernel(const float* __restrict__ in, bf16* __restrict__ out,
                                      int R, int C) {
  __shared__ float tile[32][33];
  int c0 = blockIdx.x * 32, r0 = blockIdx.y * 32;
  int tx = threadIdx.x, ty = threadIdx.y;   // 32 x 8
#pragma unroll
  for (int i = 0; i < 32; i += 8)
    tile[ty + i][tx] = in[(size_t)(r0 + ty + i) * C + (c0 + tx)];
  __syncthreads();
#pragma unroll
  for (int i = 0; i < 32; i += 8)
    out[(size_t)(c0 + ty + i) * R + (r0 + tx)] = __float2bfloat16(tile[tx][ty + i]);
}

// ---------------------------------------------------------------------------
// X [4096, 5120] bf16; row = b*16+m
// cols: [0,2048) sfeat(b) | [2048,3072) wr[b,:,m] | [3072,4096) wi[b,:,m] | [4096,5120) vM[:,m]
__global__ void build_x_kernel(const bf16* __restrict__ sfeat,
                               const float* __restrict__ wr_, const float* __restrict__ wi_,
                               const float* __restrict__ vM, bf16* __restrict__ X) {
  int row = blockIdx.x;
  int b = row >> 4, m = row & 15;
  bf16* xr = X + (size_t)row * D_;
  const bf16* sf = sfeat + (size_t)b * 2048;
  for (int c = threadIdx.x; c < 2048; c += 256) xr[c] = sf[c];
  const float* wrb = wr_ + (size_t)b * (LW_ * M_) + m;
  for (int c = threadIdx.x; c < 1024; c += 256) xr[2048 + c] = __float2bfloat16(wrb[c * 16]);
  const float* wib = wi_ + (size_t)b * (LW_ * M_) + m;
  for (int c = threadIdx.x; c < 1024; c += 256) xr[3072 + c] = __float2bfloat16(wib[c * 16]);
  for (int c = threadIdx.x; c < 1024; c += 256) xr[4096 + c] = __float2bfloat16(vM[c * 16 + m]);
}

// ---------------------------------------------------------------------------
// C = A[M,K] @ Bt[N,K]^T, 128x128 tile, BK=32, 4 waves (2x2), m97 structure.
// EPI 0: h = relu(acc + bias[c]) -> bf16 outH (row stride N1), bias split at H_
// EPI 1: out1[(r>>4)*LS*M + c*M + (r&15)] = acc + bias0[c]  (f32 scatter = eta_M^T)
template <int EPI>
__global__ void __launch_bounds__(256)
gemm_bt_kernel(const bf16* __restrict__ A, int lda,
               const bf16* __restrict__ Bt, int ldb, int K,
               const float* __restrict__ bias0, const float* __restrict__ bias1,
               bf16* __restrict__ outH, float* __restrict__ outS) {
  __shared__ __align__(16) bf16 As[128 * 32];
  __shared__ __align__(16) bf16 Bs[128 * 32];

  const int tid  = threadIdx.x;
  const int lane = tid & 63;
  const int wave = tid >> 6;
  const int wr = wave >> 1, wc = wave & 1;
  const int fr = lane & 15;   // fragment row (A) / col (B) / col (C)
  const int fq = lane >> 4;   // 0..3: k-octet select, C row group
  const int row0 = blockIdx.y * 128;
  const int col0 = blockIdx.x * 128;

  // staging decomposition: 512 chunks of 16B; chunk li -> row=li>>2, col8=(li&3)*8
  const int li0 = tid, li1 = tid + 256;
  const int r0s = li0 >> 2, c0s = (li0 & 3) << 3;
  const int r1s = li1 >> 2, c1s = (li1 & 3) << 3;

  f32x4 acc[4][4] = {};

  for (int k0 = 0; k0 < K; k0 += 32) {
    gld_lds16(A  + (size_t)(row0 + r0s) * lda + k0 + c0s, &As[li0 * 8]);
    gld_lds16(Bt + (size_t)(col0 + r0s) * ldb + k0 + c0s, &Bs[li0 * 8]);
    gld_lds16(A  + (size_t)(row0 + r1s) * lda + k0 + c1s, &As[li1 * 8]);
    gld_lds16(Bt + (size_t)(col0 + r1s) * ldb + k0 + c1s, &Bs[li1 * 8]);
    __syncthreads();

    bf16x8 a[4], b[4];
#pragma unroll
    for (int m = 0; m < 4; ++m)
      a[m] = *reinterpret_cast<const bf16x8*>(&As[(wr * 64 + m * 16 + fr) * 32 + fq * 8]);
#pragma unroll
    for (int n = 0; n < 4; ++n)
      b[n] = *reinterpret_cast<const bf16x8*>(&Bs[(wc * 64 + n * 16 + fr) * 32 + fq * 8]);
#pragma unroll
    for (int m = 0; m < 4; ++m)
#pragma unroll
      for (int n = 0; n < 4; ++n)
        acc[m][n] = __builtin_amdgcn_mfma_f32_16x16x32_bf16(a[m], b[n], acc[m][n], 0, 0, 0);
    __syncthreads();
  }

#pragma unroll
  for (int m = 0; m < 4; ++m) {
#pragma unroll
    for (int n = 0; n < 4; ++n) {
      const int c = col0 + wc * 64 + n * 16 + fr;
      float bias;
      if (EPI == 0) bias = (c < H_) ? bias0[c] : bias1[c - H_];
      else          bias = bias0[c];
#pragma unroll
      for (int j = 0; j < 4; ++j) {
        const int r = row0 + wr * 64 + m * 16 + fq * 4 + j;
        float v = acc[m][n][j] + bias;
        if (EPI == 0) {
          outH[(size_t)r * N1 + c] = __float2bfloat16(v > 0.f ? v : 0.f);
        } else {
          outS[((size_t)(r >> 4)) * (LS_ * M_) + (size_t)c * M_ + (r & 15)] = v;
        }
      }
    }
  }
}

// ---------------------------------------------------------------------------
// rho[r] = b2r + sum_h h[r, 2048+h] * W2r[h],  r in [0,4096)
__global__ void rho_kernel(const bf16* __restrict__ h, const float* __restrict__ w2r,
                           const float* __restrict__ b2r, float* __restrict__ rho) {
  int r = blockIdx.x;
  int t = threadIdx.x;            // 256 threads * 8 = 2048
  int lane = t & 63, wave = t >> 6;
  const bf16* hr = h + (size_t)r * N1 + H_;
  float s = 0.f;
#pragma unroll
  for (int j = 0; j < 8; ++j)
    s += __bfloat162float(hr[t * 8 + j]) * w2r[t * 8 + j];
#pragma unroll
  for (int off = 32; off > 0; off >>= 1) s += __shfl_down(s, off);
  __shared__ float ws4[4];
  if (lane == 0) ws4[wave] = s;
  __syncthreads();
  if (t == 0) rho[r] = ws4[0] + ws4[1] + ws4[2] + ws4[3] + b2r[0];
}

// ---------------------------------------------------------------------------
// out0[b,l] = phi[b,l] - sum_m rho[b*16+m] * etaMT[b*16384 + l*16 + m]
__global__ void finalize_kernel(const float* __restrict__ phi, const float* __restrict__ rho,
                                const float* __restrict__ etaMT, float* __restrict__ out0) {
  int i = blockIdx.x * blockDim.x + threadIdx.x;  // 0..B*LS-1
  int b = i >> 10;
  const float* em = etaMT + (size_t)i * 16;
  const float* rb = rho + b * 16;
  float s = 0.f;
#pragma unroll
  for (int m = 0; m < 16; ++m) s += rb[m] * em[m];
  out0[i] = phi[i] - s;
}

// ---------------------------------------------------------------------------
extern "C" void kernel_launch(void* const* d_in, const int* in_sizes, int n_in,
                              void* d_out, int out_size, void* d_ws, size_t ws_size,
                              hipStream_t stream) {
  const float* phi = (const float*)d_in[0];
  const float* wMr = (const float*)d_in[1];
  const float* wMi = (const float*)d_in[2];
  const float* vM  = (const float*)d_in[3];
  const float* W1e = (const float*)d_in[4];
  const float* b1e = (const float*)d_in[5];
  const float* W2e = (const float*)d_in[6];
  const float* b2e = (const float*)d_in[7];
  const float* W1r = (const float*)d_in[8];
  const float* b1r = (const float*)d_in[9];
  const float* W2r = (const float*)d_in[10];
  const float* b2r = (const float*)d_in[11];

  float* out0 = (float*)d_out;            // phi_optimal [B, LS]
  float* out1 = out0 + (size_t)B_ * LS_;  // eta_M^T     [B, LS, M]

  // workspace layout (all 16B aligned): ~123 MB
  bf16* X     = (bf16*)d_ws;                       // [4096, 5120]
  bf16* W1t   = X + (size_t)ROWS * D_;             // [4096, 5120]  (W1e|W1r)^T
  bf16* h     = W1t + (size_t)N1 * D_;             // [4096, 4096]  relu(X@W1+b)
  bf16* W2t   = h + (size_t)ROWS * N1;             // [1024, 2048]  W2e^T
  bf16* sfeat = W2t + (size_t)LS_ * H_;            // [256, 2048]
  float* rho  = (float*)(sfeat + (size_t)B_ * 2048); // [4096]

  sfeat_kernel<<<(B_ * LS_) / 256, 256, 0, stream>>>(phi, sfeat);
  dim3 tb(32, 8);
  transpose_bf16_kernel<<<dim3(H_ / 32, D_ / 32), tb, 0, stream>>>(W1e, W1t, D_, H_);
  transpose_bf16_kernel<<<dim3(H_ / 32, D_ / 32), tb, 0, stream>>>(W1r, W1t + (size_t)H_ * D_, D_, H_);
  transpose_bf16_kernel<<<dim3(LS_ / 32, H_ / 32), tb, 0, stream>>>(W2e, W2t, H_, LS_);
  build_x_kernel<<<ROWS, 256, 0, stream>>>(sfeat, wMr, wMi, vM, X);

  // GEMM1: h = relu(X @ W1t^T + bias), [4096 x 4096], K=5120
  gemm_bt_kernel<0><<<dim3(N1 / 128, ROWS / 128), 256, 0, stream>>>(
      X, D_, W1t, D_, D_, b1e, b1r, h, nullptr);

  // GEMM2: eta_M^T scatter into out1, [4096 x 1024], K=2048 (h cols [0,2048))
  gemm_bt_kernel<1><<<dim3(LS_ / 128, ROWS / 128), 256, 0, stream>>>(
      h, N1, W2t, H_, H_, b2e, nullptr, nullptr, out1);

  rho_kernel<<<ROWS, 256, 0, stream>>>(h, W2r, b2r, rho);
  finalize_kernel<<<(B_ * LS_) / 256, 256, 0, stream>>>(phi, rho, out1, out0);
}

// Round 2
// 285.359 us; speedup vs baseline: 1.3620x; 1.3620x over previous
//
#include <hip/hip_runtime.h>
#include <hip/hip_bf16.h>
#include <stdint.h>

// Problem constants
#define B_    256
#define LS_   1024
#define LW_   1024
#define LV_   1024
#define M_    16
#define D_    5120
#define H_    2048
#define ROWS  4096   // B*M
#define N1    4096   // H (eta) + H (rho) fused

typedef __hip_bfloat16 bf16;
typedef __bf16 bf16x8 __attribute__((ext_vector_type(8)));
typedef float f32x4 __attribute__((ext_vector_type(4)));

#define MEMF() asm volatile("" ::: "memory")
#define BARR() do { MEMF(); __builtin_amdgcn_s_barrier(); MEMF(); } while (0)
#define LGKM0() asm volatile("s_waitcnt lgkmcnt(0)" ::: "memory")
#define VMCNT8() asm volatile("s_waitcnt vmcnt(8)" ::: "memory")
#define VMCNT0() asm volatile("s_waitcnt vmcnt(0)" ::: "memory")

// ---------------------------------------------------------------------------
// async global->LDS, 16B per lane (HW: wave-uniform LDS base + lane*16).
__device__ __forceinline__ void gld_lds16(const void* g, void* l) {
  auto gp = (const __attribute__((address_space(1))) uint32_t*)(uintptr_t)g;
  auto lp = (__attribute__((address_space(3))) uint32_t*)(uint32_t)(uintptr_t)l;
  __builtin_amdgcn_global_load_lds(gp, lp, 16, 0, 0);
}

// ---------------------------------------------------------------------------
// s_feat: [B, 2048] bf16 : [mag*cos(phi) | mag*sin(phi)]
__global__ void sfeat_kernel(const float* __restrict__ phi, bf16* __restrict__ sfeat) {
  int i = blockIdx.x * blockDim.x + threadIdx.x;
  int b = i >> 10, l = i & 1023;
  float p = phi[i];
  float s, c;
  sincosf(p, &s, &c);
  sfeat[b * 2048 + l]        = __float2bfloat16(0.03125f * c);
  sfeat[b * 2048 + 1024 + l] = __float2bfloat16(0.03125f * s);
}

// ---------------------------------------------------------------------------
// Transpose f32 [R,C] -> bf16 [C,R]
__global__ void transpose_bf16_kernel(const float* __restrict__ in, bf16* __restrict__ out,
                                      int R, int C) {
  __shared__ float tile[32][33];
  int c0 = blockIdx.x * 32, r0 = blockIdx.y * 32;
  int tx = threadIdx.x, ty = threadIdx.y;   // 32 x 8
#pragma unroll
  for (int i = 0; i < 32; i += 8)
    tile[ty + i][tx] = in[(size_t)(r0 + ty + i) * C + (c0 + tx)];
  __syncthreads();
#pragma unroll
  for (int i = 0; i < 32; i += 8)
    out[(size_t)(c0 + ty + i) * R + (r0 + tx)] = __float2bfloat16(tile[tx][ty + i]);
}

// ---------------------------------------------------------------------------
// X [4096, 5120] bf16; row = b*16+m
__global__ void build_x_kernel(const bf16* __restrict__ sfeat,
                               const float* __restrict__ wr_, const float* __restrict__ wi_,
                               const float* __restrict__ vM, bf16* __restrict__ X) {
  int row = blockIdx.x;
  int b = row >> 4, m = row & 15;
  bf16* xr = X + (size_t)row * D_;
  const bf16* sf = sfeat + (size_t)b * 2048;
  for (int c = threadIdx.x; c < 2048; c += 256) xr[c] = sf[c];
  const float* wrb = wr_ + (size_t)b * (LW_ * M_) + m;
  for (int c = threadIdx.x; c < 1024; c += 256) xr[2048 + c] = __float2bfloat16(wrb[c * 16]);
  const float* wib = wi_ + (size_t)b * (LW_ * M_) + m;
  for (int c = threadIdx.x; c < 1024; c += 256) xr[3072 + c] = __float2bfloat16(wib[c * 16]);
  for (int c = threadIdx.x; c < 1024; c += 256) xr[4096 + c] = __float2bfloat16(vM[c * 16 + m]);
}

// ---------------------------------------------------------------------------
// GEMM1: 256x256 tile, BK=64, 8 waves (2Mx4N), 8-phase-family schedule.
// h = relu(X[4096,5120] @ W1t[4096,5120]^T + bias) -> bf16 [4096, N1]
// LDS 128 KiB: buf{0,1} x (A 32KB | B 32KB). Tile layout [256][64] bf16,
// XOR-swizzled: row's 8 16B-slots permuted by slot ^= (row&7).
__global__ void __launch_bounds__(512, 2)
gemm1_256_kernel(const bf16* __restrict__ A, const bf16* __restrict__ Bt,
                 const float* __restrict__ bias0, const float* __restrict__ bias1,
                 bf16* __restrict__ outH) {
  extern __shared__ __align__(16) char smem[];
  constexpr int LDA = D_;        // 5120 (both operands)
  constexpr int NT  = D_ / 64;   // 80 K-tiles

  const int tid  = threadIdx.x;
  const int lane = tid & 63;
  const int wave = tid >> 6;
  const int wr = wave >> 2, wc = wave & 3;   // 2 x 4 wave grid
  const int fr = lane & 15, fq = lane >> 4;
  const int row0 = blockIdx.y * 256, col0 = blockIdx.x * 256;

  // staging: thread li covers (local row rl, slot sl); global col pre-swizzled
  const int rl = tid >> 3, sl = tid & 7;
  const int srcCol = ((sl ^ (rl & 7)) << 4);        // byte offset within 128B row
  const char* Ab = (const char*)A;
  const char* Bb = (const char*)Bt;

  // ds_read fragment offsets (swizzled slot)
  const int xr  = fr & 7;
  const int sA0 = ((fq ^ xr) << 4);                 // kstep 0
  const int sA1 = (((4 + fq) ^ xr) << 4);           // kstep 1
  const int aBase = (wr * 128 + fr) << 7;
  const int bBase = 32768 + ((wc * 64 + fr) << 7);

  char* buf0 = smem;
  char* buf1 = smem + 65536;

  auto stage = [&](const char* gb, int grow0, int kt, int p, char* dst, int dOff) {
    const char* g = gb + ((size_t)(grow0 + p * 64 + rl) * LDA + (size_t)kt * 64) * 2 + srcCol;
    gld_lds16(g, dst + dOff + p * 8192 + tid * 16);
  };

  f32x4 acc[8][4] = {};

  // prologue: tile0 -> buf0, tile1 -> buf1 (16 loads); retire tile0, keep tile1 flying
#pragma unroll
  for (int p = 0; p < 4; ++p) stage(Ab, row0, 0, p, buf0, 0);
#pragma unroll
  for (int p = 0; p < 4; ++p) stage(Bb, col0, 0, p, buf0, 32768);
#pragma unroll
  for (int p = 0; p < 4; ++p) stage(Ab, row0, 1, p, buf1, 0);
#pragma unroll
  for (int p = 0; p < 4; ++p) stage(Bb, col0, 1, p, buf1, 32768);
  VMCNT8();
  BARR();

  for (int t = 0; t < NT; ++t) {
    char* cur = (t & 1) ? buf1 : buf0;   // tile t's data; also staging target for t+2
    const int kt2 = t + 2;
    const bool pf = (kt2 < NT);
    bf16x8 a[8][2], bLo[2][2], bHi[2][2];

    // ---- P1: read a[0..3], bLo; MFMA m0-3 x n0-1
#pragma unroll
    for (int m = 0; m < 4; ++m) {
      a[m][0] = *(const bf16x8*)(cur + aBase + m * 2048 + sA0);
      a[m][1] = *(const bf16x8*)(cur + aBase + m * 2048 + sA1);
    }
#pragma unroll
    for (int n = 0; n < 2; ++n) {
      bLo[n][0] = *(const bf16x8*)(cur + bBase + n * 2048 + sA0);
      bLo[n][1] = *(const bf16x8*)(cur + bBase + n * 2048 + sA1);
    }
    BARR(); LGKM0();
    __builtin_amdgcn_s_setprio(1);
#pragma unroll
    for (int m = 0; m < 4; ++m)
#pragma unroll
      for (int n = 0; n < 2; ++n) {
        acc[m][n] = __builtin_amdgcn_mfma_f32_16x16x32_bf16(a[m][0], bLo[n][0], acc[m][n], 0, 0, 0);
        acc[m][n] = __builtin_amdgcn_mfma_f32_16x16x32_bf16(a[m][1], bLo[n][1], acc[m][n], 0, 0, 0);
      }
    __builtin_amdgcn_s_setprio(0);
    LGKM0();   // all P1 reads retired before anyone proceeds (A-region reuse guard)
    BARR();

    // ---- P2: read a[4..7]; MFMA m4-7 x n0-1
#pragma unroll
    for (int m = 4; m < 8; ++m) {
      a[m][0] = *(const bf16x8*)(cur + aBase + m * 2048 + sA0);
      a[m][1] = *(const bf16x8*)(cur + aBase + m * 2048 + sA1);
    }
    BARR(); LGKM0();
    __builtin_amdgcn_s_setprio(1);
#pragma unroll
    for (int m = 4; m < 8; ++m)
#pragma unroll
      for (int n = 0; n < 2; ++n) {
        acc[m][n] = __builtin_amdgcn_mfma_f32_16x16x32_bf16(a[m][0], bLo[n][0], acc[m][n], 0, 0, 0);
        acc[m][n] = __builtin_amdgcn_mfma_f32_16x16x32_bf16(a[m][1], bLo[n][1], acc[m][n], 0, 0, 0);
      }
    __builtin_amdgcn_s_setprio(0);
    LGKM0();   // A-region fully consumed -> A staging may land
    BARR();

    // ---- P3: read bHi; stage A(t+2) -> cur; MFMA m0-3 x n2-3
#pragma unroll
    for (int n = 0; n < 2; ++n) {
      bHi[n][0] = *(const bf16x8*)(cur + bBase + (n + 2) * 2048 + sA0);
      bHi[n][1] = *(const bf16x8*)(cur + bBase + (n + 2) * 2048 + sA1);
    }
    if (pf) {
#pragma unroll
      for (int p = 0; p < 4; ++p) stage(Ab, row0, kt2, p, cur, 0);
    }
    BARR(); LGKM0();
    __builtin_amdgcn_s_setprio(1);
#pragma unroll
    for (int m = 0; m < 4; ++m)
#pragma unroll
      for (int n = 0; n < 2; ++n) {
        acc[m][n + 2] = __builtin_amdgcn_mfma_f32_16x16x32_bf16(a[m][0], bHi[n][0], acc[m][n + 2], 0, 0, 0);
        acc[m][n + 2] = __builtin_amdgcn_mfma_f32_16x16x32_bf16(a[m][1], bHi[n][1], acc[m][n + 2], 0, 0, 0);
      }
    __builtin_amdgcn_s_setprio(0);
    LGKM0();   // B-region fully consumed -> B staging may land
    BARR();

    // ---- P4: stage B(t+2) -> cur; counted vmcnt releases tile t+1; MFMA m4-7 x n2-3
    if (pf) {
#pragma unroll
      for (int p = 0; p < 4; ++p) stage(Bb, col0, kt2, p, cur, 32768);
      VMCNT8();   // retire tile t+1's 8 loads; keep tile t+2's 8 in flight
    } else {
      VMCNT0();   // tail: drain everything
    }
    BARR();
    __builtin_amdgcn_s_setprio(1);
#pragma unroll
    for (int m = 4; m < 8; ++m)
#pragma unroll
      for (int n = 0; n < 2; ++n) {
        acc[m][n + 2] = __builtin_amdgcn_mfma_f32_16x16x32_bf16(a[m][0], bHi[n][0], acc[m][n + 2], 0, 0, 0);
        acc[m][n + 2] = __builtin_amdgcn_mfma_f32_16x16x32_bf16(a[m][1], bHi[n][1], acc[m][n + 2], 0, 0, 0);
      }
    __builtin_amdgcn_s_setprio(0);
    BARR();
  }

  // epilogue: bias + relu -> bf16
#pragma unroll
  for (int m = 0; m < 8; ++m) {
#pragma unroll
    for (int n = 0; n < 4; ++n) {
      const int c = col0 + wc * 64 + n * 16 + fr;
      const float bias = (c < H_) ? bias0[c] : bias1[c - H_];
#pragma unroll
      for (int j = 0; j < 4; ++j) {
        const int r = row0 + wr * 128 + m * 16 + fq * 4 + j;
        float v = acc[m][n][j] + bias;
        outH[(size_t)r * N1 + c] = __float2bfloat16(v > 0.f ? v : 0.f);
      }
    }
  }
}

// ---------------------------------------------------------------------------
// 128x128 m97-style GEMM (kept for GEMM2): out1 scatter = eta_M^T
__global__ void __launch_bounds__(256)
gemm2_bt_kernel(const bf16* __restrict__ A, int lda,
                const bf16* __restrict__ Bt, int ldb, int K,
                const float* __restrict__ bias0, float* __restrict__ outS) {
  __shared__ __align__(16) bf16 As[128 * 32];
  __shared__ __align__(16) bf16 Bs[128 * 32];

  const int tid  = threadIdx.x;
  const int lane = tid & 63;
  const int wave = tid >> 6;
  const int wr = wave >> 1, wc = wave & 1;
  const int fr = lane & 15;
  const int fq = lane >> 4;
  const int row0 = blockIdx.y * 128;
  const int col0 = blockIdx.x * 128;

  const int li0 = tid, li1 = tid + 256;
  const int r0s = li0 >> 2, c0s = (li0 & 3) << 3;
  const int r1s = li1 >> 2, c1s = (li1 & 3) << 3;

  f32x4 acc[4][4] = {};

  for (int k0 = 0; k0 < K; k0 += 32) {
    gld_lds16(A  + (size_t)(row0 + r0s) * lda + k0 + c0s, &As[li0 * 8]);
    gld_lds16(Bt + (size_t)(col0 + r0s) * ldb + k0 + c0s, &Bs[li0 * 8]);
    gld_lds16(A  + (size_t)(row0 + r1s) * lda + k0 + c1s, &As[li1 * 8]);
    gld_lds16(Bt + (size_t)(col0 + r1s) * ldb + k0 + c1s, &Bs[li1 * 8]);
    __syncthreads();

    bf16x8 a[4], b[4];
#pragma unroll
    for (int m = 0; m < 4; ++m)
      a[m] = *reinterpret_cast<const bf16x8*>(&As[(wr * 64 + m * 16 + fr) * 32 + fq * 8]);
#pragma unroll
    for (int n = 0; n < 4; ++n)
      b[n] = *reinterpret_cast<const bf16x8*>(&Bs[(wc * 64 + n * 16 + fr) * 32 + fq * 8]);
#pragma unroll
    for (int m = 0; m < 4; ++m)
#pragma unroll
      for (int n = 0; n < 4; ++n)
        acc[m][n] = __builtin_amdgcn_mfma_f32_16x16x32_bf16(a[m], b[n], acc[m][n], 0, 0, 0);
    __syncthreads();
  }

#pragma unroll
  for (int m = 0; m < 4; ++m) {
#pragma unroll
    for (int n = 0; n < 4; ++n) {
      const int c = col0 + wc * 64 + n * 16 + fr;
      const float bias = bias0[c];
#pragma unroll
      for (int j = 0; j < 4; ++j) {
        const int r = row0 + wr * 64 + m * 16 + fq * 4 + j;
        outS[((size_t)(r >> 4)) * (LS_ * M_) + (size_t)c * M_ + (r & 15)] = acc[m][n][j] + bias;
      }
    }
  }
}

// ---------------------------------------------------------------------------
__global__ void rho_kernel(const bf16* __restrict__ h, const float* __restrict__ w2r,
                           const float* __restrict__ b2r, float* __restrict__ rho) {
  int r = blockIdx.x;
  int t = threadIdx.x;
  int lane = t & 63, wave = t >> 6;
  const bf16* hr = h + (size_t)r * N1 + H_;
  float s = 0.f;
#pragma unroll
  for (int j = 0; j < 8; ++j)
    s += __bfloat162float(hr[t * 8 + j]) * w2r[t * 8 + j];
#pragma unroll
  for (int off = 32; off > 0; off >>= 1) s += __shfl_down(s, off);
  __shared__ float ws4[4];
  if (lane == 0) ws4[wave] = s;
  __syncthreads();
  if (t == 0) rho[r] = ws4[0] + ws4[1] + ws4[2] + ws4[3] + b2r[0];
}

// ---------------------------------------------------------------------------
__global__ void finalize_kernel(const float* __restrict__ phi, const float* __restrict__ rho,
                                const float* __restrict__ etaMT, float* __restrict__ out0) {
  int i = blockIdx.x * blockDim.x + threadIdx.x;
  int b = i >> 10;
  const float* em = etaMT + (size_t)i * 16;
  const float* rb = rho + b * 16;
  float s = 0.f;
#pragma unroll
  for (int m = 0; m < 16; ++m) s += rb[m] * em[m];
  out0[i] = phi[i] - s;
}

// ---------------------------------------------------------------------------
extern "C" void kernel_launch(void* const* d_in, const int* in_sizes, int n_in,
                              void* d_out, int out_size, void* d_ws, size_t ws_size,
                              hipStream_t stream) {
  const float* phi = (const float*)d_in[0];
  const float* wMr = (const float*)d_in[1];
  const float* wMi = (const float*)d_in[2];
  const float* vM  = (const float*)d_in[3];
  const float* W1e = (const float*)d_in[4];
  const float* b1e = (const float*)d_in[5];
  const float* W2e = (const float*)d_in[6];
  const float* b2e = (const float*)d_in[7];
  const float* W1r = (const float*)d_in[8];
  const float* b1r = (const float*)d_in[9];
  const float* W2r = (const float*)d_in[10];
  const float* b2r = (const float*)d_in[11];

  float* out0 = (float*)d_out;            // phi_optimal [B, LS]
  float* out1 = out0 + (size_t)B_ * LS_;  // eta_M^T     [B, LS, M]

  bf16* X     = (bf16*)d_ws;                         // [4096, 5120]
  bf16* W1t   = X + (size_t)ROWS * D_;               // [4096, 5120]
  bf16* h     = W1t + (size_t)N1 * D_;               // [4096, 4096]
  bf16* W2t   = h + (size_t)ROWS * N1;               // [1024, 2048]
  bf16* sfeat = W2t + (size_t)LS_ * H_;              // [256, 2048]
  float* rho  = (float*)(sfeat + (size_t)B_ * 2048); // [4096]

  (void)hipFuncSetAttribute(reinterpret_cast<const void*>(gemm1_256_kernel),
                            hipFuncAttributeMaxDynamicSharedMemorySize, 131072);

  sfeat_kernel<<<(B_ * LS_) / 256, 256, 0, stream>>>(phi, sfeat);
  dim3 tb(32, 8);
  transpose_bf16_kernel<<<dim3(H_ / 32, D_ / 32), tb, 0, stream>>>(W1e, W1t, D_, H_);
  transpose_bf16_kernel<<<dim3(H_ / 32, D_ / 32), tb, 0, stream>>>(W1r, W1t + (size_t)H_ * D_, D_, H_);
  transpose_bf16_kernel<<<dim3(LS_ / 32, H_ / 32), tb, 0, stream>>>(W2e, W2t, H_, LS_);
  build_x_kernel<<<ROWS, 256, 0, stream>>>(sfeat, wMr, wMi, vM, X);

  // GEMM1: 256^2 8-phase, h = relu(X @ W1t^T + bias), [4096 x 4096], K=5120
  gemm1_256_kernel<<<dim3(N1 / 256, ROWS / 256), 512, 131072, stream>>>(
      X, W1t, b1e, b1r, h);

  // GEMM2: eta_M^T scatter into out1, [4096 x 1024], K=2048
  gemm2_bt_kernel<<<dim3(LS_ / 128, ROWS / 128), 256, 0, stream>>>(
      h, N1, W2t, H_, H_, b2e, out1);

  rho_kernel<<<ROWS, 256, 0, stream>>>(h, W2r, b2r, rho);
  finalize_kernel<<<(B_ * LS_) / 256, 256, 0, stream>>>(phi, rho, out1, out0);
}